// Round 9
// baseline (206.701 us; speedup 1.0000x reference)
//
#include <hip/hip_runtime.h>
#include <stdint.h>

// Workspace layout (~48.6 MB):
//   xh    @ 0      : [4096][1024] bf16 (8 MB)  x hi part (= K hi)
//   xl    @ 8 MB   : [4096][1024] bf16 (8 MB)  x lo part
//   Wh    @ 16 MB  : [2048][1024] bf16 (4 MB)  W_qv^T hi
//   Wl    @ 20 MB  : [2048][1024] bf16 (4 MB)  W_qv^T lo
//   qwsf  @ 24 MB  : [8][16][512][64] f32 (16 MB) q full f32
//   vt    @ 40 MB  : [8][16][64][512] bf16 (8 MB) v transposed per head
//   poshi @ 48 MB          : [1088][64] bf16
//   poslo @ 48 MB + 192 KB : [1088][64] bf16
//   posf  @ 48 MB + 384 KB : [512][64] f32 = sin/cos(k*f_j)
//
// R9: k_gemm back to reg-staging (stride-40 pad, conflict-free: gload_lds's
// stride-32 layout was 8-way conflicted, 3.1M/dispatch) but with T14
// early-issue (loads for t+1 issued before compute of t). k_attn: 2 q-tiles
// per block sharing staged K/V/T (T is q-independent), grid(bh, qpair) so
// same-bh blocks share an XCD's L2 for K/V; 512 blocks = no tail.

typedef __attribute__((ext_vector_type(8))) short s8v;
typedef __attribute__((ext_vector_type(4))) float f4v;

#define MFMA_BF16 __builtin_amdgcn_mfma_f32_16x16x32_bf16

__device__ __forceinline__ float bf2f(unsigned short s) {
  unsigned int u = ((unsigned int)s) << 16;
  float f;
  __builtin_memcpy(&f, &u, 4);
  return f;
}
__device__ __forceinline__ unsigned short f2bf(float f) {
  unsigned int u;
  __builtin_memcpy(&u, &f, 4);
  unsigned int r = (u + 0x7fffu + ((u >> 16) & 1u)) >> 16;
  return (unsigned short)r;
}
__device__ __forceinline__ bool is_bf16_in(const void* mask) {
  return (((const unsigned int*)mask)[0] & 0xFFFFu) != 0u;
}

// ---------------- split x -> xh, xl (bf16 hi/lo) ----------------
__global__ __launch_bounds__(256) void k_split_x(const void* __restrict__ X,
                                                 const void* __restrict__ mask,
                                                 unsigned short* __restrict__ xh,
                                                 unsigned short* __restrict__ xl) {
  const bool isb = is_bf16_in(mask);
  const int i = (blockIdx.x * 256 + threadIdx.x) * 8;
  s8v oh, ol;
  if (isb) {
    oh = *(const s8v*)((const unsigned short*)X + i);
#pragma unroll
    for (int j = 0; j < 8; ++j) ol[j] = 0;
  } else {
    const float* xf = (const float*)X + i;
#pragma unroll
    for (int j = 0; j < 8; ++j) {
      float v = xf[j];
      unsigned short hi = f2bf(v);
      oh[j] = (short)hi;
      ol[j] = (short)f2bf(v - bf2f(hi));
    }
  }
  *(s8v*)(xh + i) = oh;
  *(s8v*)(xl + i) = ol;
}

// ------- W transpose+split: W[1024][2048] -> Wh/Wl[2048][1024] bf16 -------
__global__ __launch_bounds__(256) void k_transpose(const void* __restrict__ W,
                                                   const void* __restrict__ mask,
                                                   unsigned short* __restrict__ Wh,
                                                   unsigned short* __restrict__ Wl) {
  __shared__ unsigned short th[64][65];
  __shared__ unsigned short tl[64][65];
  const bool isb = is_bf16_in(mask);
  const int n0 = blockIdx.x * 64;
  const int k0 = blockIdx.y * 64;
  const int t = threadIdx.x;
#pragma unroll
  for (int i = 0; i < 16; ++i) {
    int idx = t + i * 256;
    int kl = idx >> 6, nl = idx & 63;
    int src = (k0 + kl) * 2048 + n0 + nl;
    unsigned short hi, lo;
    if (isb) {
      hi = ((const unsigned short*)W)[src];
      lo = 0;
    } else {
      float v = ((const float*)W)[src];
      hi = f2bf(v);
      lo = f2bf(v - bf2f(hi));
    }
    th[nl][kl] = hi;
    tl[nl][kl] = lo;
  }
  __syncthreads();
#pragma unroll
  for (int i = 0; i < 16; ++i) {
    int idx = t + i * 256;
    int nl = idx >> 6, kl = idx & 63;
    Wh[(n0 + nl) * 1024 + k0 + kl] = th[nl][kl];
    Wl[(n0 + nl) * 1024 + k0 + kl] = tl[nl][kl];
  }
}

// ---- pos tables: hi/lo split bf16 [1088][64] + f32 posf[512][64] ----
__global__ __launch_bounds__(256) void k_pos(unsigned short* __restrict__ poshi,
                                             unsigned short* __restrict__ poslo,
                                             float* __restrict__ posf) {
  int idx = blockIdx.x * 256 + threadIdx.x;
  if (idx >= 1088 * 64) return;
  int l = idx >> 6, i = idx & 63;
  unsigned short hi = 0, lo = 0;
  if (l < 1024) {
    int j = i & 31;
    float f = expf(-0.2971077539347156f * (float)j);  // -ln(10000)/31
    float ang = (float)(l - 512) * f;
    float v = (i < 32) ? sinf(ang) : cosf(ang);
    hi = f2bf(v);
    lo = f2bf(v - bf2f(hi));
    if (l >= 512) posf[(l - 512) * 64 + i] = v;
  }
  poshi[idx] = hi;
  poslo[idx] = lo;
}

// ---- qv GEMM v3: reg-staged T14, stride-40 pad (conflict-free) ----
__global__ __launch_bounds__(256, 2) void k_gemm(const unsigned short* __restrict__ xh,
                                                 const unsigned short* __restrict__ xl,
                                                 const unsigned short* __restrict__ Wh,
                                                 const unsigned short* __restrict__ Wl,
                                                 float* __restrict__ qwsf,
                                                 unsigned short* __restrict__ vt) {
  __shared__ unsigned short Ah[128 * 40];
  __shared__ unsigned short Bh[128 * 40];
  __shared__ unsigned short Al2[128 * 40];
  __shared__ unsigned short Bl2[128 * 40];
  const int m0 = blockIdx.y * 128;
  const int n0 = blockIdx.x * 128;
  const bool isq = (n0 < 1024);
  const int t = threadIdx.x;
  const int w = t >> 6, lane = t & 63;
  const int wr = w >> 1, wc = w & 1;
  const int l16 = lane & 15, g = lane >> 4;

  const int ca = t, cb = t + 256;
  const int ra = ca >> 2, ka = (ca & 3) * 8, rb = cb >> 2, kb = (cb & 3) * 8;

  f4v acc[4][4];
#pragma unroll
  for (int i = 0; i < 4; ++i)
#pragma unroll
    for (int j = 0; j < 4; ++j) acc[i][j] = (f4v){0.f, 0.f, 0.f, 0.f};

  // prologue: load + write tile 0
  s8v sA0, sA1, sB0, sB1, sC0, sC1, sD0, sD1;
  auto issue = [&](int k0) {
    sA0 = *(const s8v*)&xh[(m0 + ra) * 1024 + k0 + ka];
    sA1 = *(const s8v*)&xh[(m0 + rb) * 1024 + k0 + kb];
    sB0 = *(const s8v*)&Wh[(n0 + ra) * 1024 + k0 + ka];
    sB1 = *(const s8v*)&Wh[(n0 + rb) * 1024 + k0 + kb];
    if (isq) {
      sC0 = *(const s8v*)&xl[(m0 + ra) * 1024 + k0 + ka];
      sC1 = *(const s8v*)&xl[(m0 + rb) * 1024 + k0 + kb];
      sD0 = *(const s8v*)&Wl[(n0 + ra) * 1024 + k0 + ka];
      sD1 = *(const s8v*)&Wl[(n0 + rb) * 1024 + k0 + kb];
    }
  };
  auto commit = [&]() {
    *(s8v*)&Ah[ra * 40 + ka] = sA0;
    *(s8v*)&Ah[rb * 40 + kb] = sA1;
    *(s8v*)&Bh[ra * 40 + ka] = sB0;
    *(s8v*)&Bh[rb * 40 + kb] = sB1;
    if (isq) {
      *(s8v*)&Al2[ra * 40 + ka] = sC0;
      *(s8v*)&Al2[rb * 40 + kb] = sC1;
      *(s8v*)&Bl2[ra * 40 + ka] = sD0;
      *(s8v*)&Bl2[rb * 40 + kb] = sD1;
    }
  };
  issue(0);
  commit();
  __syncthreads();

#pragma unroll 1
  for (int t32 = 0; t32 < 32; ++t32) {
    if (t32 < 31) issue((t32 + 1) * 32);  // T14: in flight during compute
    s8v afh[4], bfh[4];
#pragma unroll
    for (int i = 0; i < 4; ++i) afh[i] = *(const s8v*)&Ah[(wr * 64 + i * 16 + l16) * 40 + g * 8];
#pragma unroll
    for (int j = 0; j < 4; ++j) bfh[j] = *(const s8v*)&Bh[(wc * 64 + j * 16 + l16) * 40 + g * 8];
    if (isq) {
      s8v afl[4], bfl[4];
#pragma unroll
      for (int i = 0; i < 4; ++i) afl[i] = *(const s8v*)&Al2[(wr * 64 + i * 16 + l16) * 40 + g * 8];
#pragma unroll
      for (int j = 0; j < 4; ++j) bfl[j] = *(const s8v*)&Bl2[(wc * 64 + j * 16 + l16) * 40 + g * 8];
#pragma unroll
      for (int i = 0; i < 4; ++i)
#pragma unroll
        for (int j = 0; j < 4; ++j) {
          acc[i][j] = MFMA_BF16(afh[i], bfh[j], acc[i][j], 0, 0, 0);
          acc[i][j] = MFMA_BF16(afl[i], bfh[j], acc[i][j], 0, 0, 0);
          acc[i][j] = MFMA_BF16(afh[i], bfl[j], acc[i][j], 0, 0, 0);
        }
    } else {
#pragma unroll
      for (int i = 0; i < 4; ++i)
#pragma unroll
        for (int j = 0; j < 4; ++j) acc[i][j] = MFMA_BF16(afh[i], bfh[j], acc[i][j], 0, 0, 0);
    }
    if (t32 < 31) {
      __syncthreads();  // all waves done reading
      commit();         // reg dep waits vmcnt as needed
      __syncthreads();  // writes visible
    }
  }

#pragma unroll
  for (int i = 0; i < 4; ++i) {
#pragma unroll
    for (int j = 0; j < 4; ++j) {
      int col = n0 + wc * 64 + j * 16 + l16;
#pragma unroll
      for (int jj = 0; jj < 4; ++jj) {
        int row = m0 + wr * 64 + i * 16 + g * 4 + jj;
        int bb = row >> 9, l = row & 511;
        if (isq) {
          int hh = col >> 6, d = col & 63;
          qwsf[((bb * 16 + hh) * 512 + l) * 64 + d] = acc[i][j][jj];
        } else {
          int c2 = col - 1024;
          int hh = c2 >> 6, d = c2 & 63;
          vt[((bb * 16 + hh) * 64 + d) * 512 + l] = f2bf(acc[i][j][jj]);
        }
      }
    }
  }
}

// -------- fused relative attention v5: 2 q-tiles/block, XCD-local KV --------
// grid(128, 4): x = bh (XCD = bh%8), y = qpair; block rows [y*128, y*128+128)
__global__ __launch_bounds__(256, 2) void k_attn(const unsigned short* __restrict__ xh,
                                                 const unsigned short* __restrict__ xl,
                                                 const float* __restrict__ qwsf,
                                                 const unsigned short* __restrict__ vt,
                                                 const unsigned short* __restrict__ poshi,
                                                 const unsigned short* __restrict__ poslo,
                                                 const float* __restrict__ posf,
                                                 const void* __restrict__ rrb,
                                                 const void* __restrict__ rwb,
                                                 const void* __restrict__ mask,
                                                 void* __restrict__ out) {
  __shared__ unsigned short Kh[64 * 64];
  __shared__ unsigned short Kl[64 * 64];
  __shared__ unsigned short Vv[64 * 64];
  __shared__ unsigned short Th[64 * 64];
  __shared__ unsigned short Tl[64 * 64];
  __shared__ unsigned short P[4][16][68];

  const bool isb = is_bf16_in(mask);
  const int bh = blockIdx.x;
  const int qp = blockIdx.y;
  const int b = bh >> 4, h = bh & 15;
  const int q0 = qp << 7;  // 128 rows per block, two 64-row halves
  const int t = threadIdx.x;
  const int w = t >> 6;
  const int lane = t & 63;
  const int l16 = lane & 15;
  const int g = lane >> 4;
  const int bh64 = (b * 16 + h) * 64;

  const int srow = t >> 3;
  const int swz = ((t & 7) ^ (srow & 7)) << 3;
  const int scc = (t & 7) * 8;

#pragma unroll
  for (int i = 0; i < 2; ++i) {
    int row = srow + i * 32;
    *(s8v*)&Kh[row * 64 + swz] = *(const s8v*)&xh[(b * 512 + row) * 1024 + h * 64 + scc];
    *(s8v*)&Kl[row * 64 + swz] = *(const s8v*)&xl[(b * 512 + row) * 1024 + h * 64 + scc];
    *(s8v*)&Vv[row * 64 + swz] = *(const s8v*)&vt[(bh64 + row) * 512 + scc];
    *(s8v*)&Th[row * 64 + swz] = *(const s8v*)&poshi[(512 + row) * 64 + scc];
    *(s8v*)&Tl[row * 64 + swz] = *(const s8v*)&poslo[(512 + row) * 64 + scc];
  }

  // ---- Q prep for both 64-row halves ----
  s8v qrh[2][2], qrl[2][2], qth[2][2], qtl[2][2];
#pragma unroll
  for (int hh = 0; hh < 2; ++hh) {
    const int qrow = q0 + hh * 64 + (w << 4) + l16;
    const float* qb = &qwsf[((b * 16 + h) * 512 + qrow) * 64];
    float qw2[2][8];
#pragma unroll
    for (int f = 0; f < 2; ++f) {
      int d0 = f * 32 + g * 8;
#pragma unroll
      for (int j = 0; j < 8; ++j) {
        float qf = qb[d0 + j];
        float b1 = isb ? bf2f(((const unsigned short*)rrb)[h * 64 + d0 + j])
                       : ((const float*)rrb)[h * 64 + d0 + j];
        float b2 = isb ? bf2f(((const unsigned short*)rwb)[h * 64 + d0 + j])
                       : ((const float*)rwb)[h * 64 + d0 + j];
        float s1 = qf + b1;
        unsigned short h1 = f2bf(s1);
        qrh[hh][f][j] = (short)h1;
        qrl[hh][f][j] = (short)f2bf(s1 - bf2f(h1));
        qw2[f][j] = qf + b2;
      }
    }
#pragma unroll
    for (int j = 0; j < 8; ++j) {
      int jd = g * 8 + j;
      float s = posf[qrow * 64 + jd];
      float c = posf[qrow * 64 + 32 + jd];
      float qs = qw2[0][j], qc = qw2[1][j];
      float Qp = qs * c + qc * s;
      float Qpp = qc * c - qs * s;
      unsigned short h0 = f2bf(Qp);
      qth[hh][0][j] = (short)h0;
      qtl[hh][0][j] = (short)f2bf(Qp - bf2f(h0));
      unsigned short h1 = f2bf(Qpp);
      qth[hh][1][j] = (short)h1;
      qtl[hh][1][j] = (short)f2bf(Qpp - bf2f(h1));
    }
  }

  f4v accO[2][4];
#pragma unroll
  for (int hh = 0; hh < 2; ++hh)
#pragma unroll
    for (int d = 0; d < 4; ++d) accO[hh][d] = (f4v){0.f, 0.f, 0.f, 0.f};
  float mrun[2][4], lrun[2][4];
#pragma unroll
  for (int hh = 0; hh < 2; ++hh)
#pragma unroll
    for (int jj = 0; jj < 4; ++jj) { mrun[hh][jj] = -3.0e38f; lrun[hh][jj] = 0.f; }

  __syncthreads();

#pragma unroll 1
  for (int kt = 0; kt < 8; ++kt) {
    const int k0 = kt << 6;

    s8v nKh[2], nKl[2], nV[2], nTh[2], nTl[2];
    const bool hasNext = (kt < 7);
    if (hasNext) {
      const int k0n = k0 + 64;
#pragma unroll
      for (int i = 0; i < 2; ++i) {
        int row = srow + i * 32;
        nKh[i] = *(const s8v*)&xh[(b * 512 + k0n + row) * 1024 + h * 64 + scc];
        nKl[i] = *(const s8v*)&xl[(b * 512 + k0n + row) * 1024 + h * 64 + scc];
        nV[i] = *(const s8v*)&vt[(bh64 + row) * 512 + k0n + scc];
        nTh[i] = *(const s8v*)&poshi[(512 + k0n + row) * 64 + scc];
        nTl[i] = *(const s8v*)&poslo[(512 + k0n + row) * 64 + scc];
      }
    }

    float mv[4];
#pragma unroll
    for (int ct = 0; ct < 4; ++ct) {
      int mi = b * 512 + k0 + ct * 16 + l16;
      mv[ct] = isb ? bf2f(((const unsigned short*)mask)[mi]) : ((const float*)mask)[mi];
    }

#pragma unroll
    for (int hh = 0; hh < 2; ++hh) {
      f4v acc[4];
#pragma unroll
      for (int ct = 0; ct < 4; ++ct) acc[ct] = (f4v){0.f, 0.f, 0.f, 0.f};
#pragma unroll
      for (int f = 0; f < 2; ++f) {
#pragma unroll
        for (int ct = 0; ct < 4; ++ct) {
          const int kr = ct * 16 + l16;
          const int eo = (((4 * f + g) ^ (l16 & 7)) << 3);
          s8v kh = *(const s8v*)&Kh[kr * 64 + eo];
          s8v klo = *(const s8v*)&Kl[kr * 64 + eo];
          s8v ph = *(const s8v*)&Th[kr * 64 + eo];
          s8v pl = *(const s8v*)&Tl[kr * 64 + eo];
          acc[ct] = MFMA_BF16(qrh[hh][f], kh, acc[ct], 0, 0, 0);
          acc[ct] = MFMA_BF16(qrl[hh][f], kh, acc[ct], 0, 0, 0);
          acc[ct] = MFMA_BF16(qrh[hh][f], klo, acc[ct], 0, 0, 0);
          acc[ct] = MFMA_BF16(qth[hh][f], ph, acc[ct], 0, 0, 0);
          acc[ct] = MFMA_BF16(qtl[hh][f], ph, acc[ct], 0, 0, 0);
          acc[ct] = MFMA_BF16(qth[hh][f], pl, acc[ct], 0, 0, 0);
        }
      }

      float sv[4][4];
#pragma unroll
      for (int ct = 0; ct < 4; ++ct) {
#pragma unroll
        for (int jj = 0; jj < 4; ++jj) {
          float s = acc[ct][jj] * mv[ct];
          if (s == 0.f) s = -__builtin_inff();
          sv[ct][jj] = s;
        }
      }

      float sc[4];
#pragma unroll
      for (int jj = 0; jj < 4; ++jj) {
        float pm = fmaxf(fmaxf(sv[0][jj], sv[1][jj]), fmaxf(sv[2][jj], sv[3][jj]));
        pm = fmaxf(pm, __shfl_xor(pm, 1));
        pm = fmaxf(pm, __shfl_xor(pm, 2));
        pm = fmaxf(pm, __shfl_xor(pm, 4));
        pm = fmaxf(pm, __shfl_xor(pm, 8));
        float mnew = fmaxf(mrun[hh][jj], pm);
        float scale = __expf(mrun[hh][jj] - mnew);
        float ps = 0.f;
#pragma unroll
        for (int ct = 0; ct < 4; ++ct) {
          float p = __expf(sv[ct][jj] - mnew);
          unsigned short pb = f2bf(p);
          P[w][4 * g + jj][ct * 16 + l16] = pb;
          ps += bf2f(pb);
        }
        ps += __shfl_xor(ps, 1);
        ps += __shfl_xor(ps, 2);
        ps += __shfl_xor(ps, 4);
        ps += __shfl_xor(ps, 8);
        lrun[hh][jj] = lrun[hh][jj] * scale + ps;
        mrun[hh][jj] = mnew;
        sc[jj] = scale;
      }

#pragma unroll
      for (int d = 0; d < 4; ++d)
#pragma unroll
        for (int jj = 0; jj < 4; ++jj) accO[hh][d][jj] *= sc[jj];
#pragma unroll
      for (int ks = 0; ks < 2; ++ks) {
        s8v pf = *(const s8v*)&P[w][l16][ks * 32 + g * 8];
#pragma unroll
        for (int d = 0; d < 4; ++d) {
          const int vr = d * 16 + l16;
          const int eo = (((4 * ks + g) ^ (l16 & 7)) << 3);
          s8v vf = *(const s8v*)&Vv[vr * 64 + eo];
          accO[hh][d] = MFMA_BF16(pf, vf, accO[hh][d], 0, 0, 0);
        }
      }
    }

    __syncthreads();
    if (hasNext) {
#pragma unroll
      for (int i = 0; i < 2; ++i) {
        int row = srow + i * 32;
        *(s8v*)&Kh[row * 64 + swz] = nKh[i];
        *(s8v*)&Kl[row * 64 + swz] = nKl[i];
        *(s8v*)&Vv[row * 64 + swz] = nV[i];
        *(s8v*)&Th[row * 64 + swz] = nTh[i];
        *(s8v*)&Tl[row * 64 + swz] = nTl[i];
      }
    }
    __syncthreads();
  }

#pragma unroll
  for (int hh = 0; hh < 2; ++hh) {
    float inv[4];
#pragma unroll
    for (int jj = 0; jj < 4; ++jj) inv[jj] = 1.0f / lrun[hh][jj];
#pragma unroll
    for (int d = 0; d < 4; ++d) {
#pragma unroll
      for (int jj = 0; jj < 4; ++jj) {
        int row = q0 + hh * 64 + (w << 4) + 4 * g + jj;
        int idx = (b * 512 + row) * 1024 + h * 64 + d * 16 + l16;
        float val = accO[hh][d][jj] * inv[jj];
        if (isb) ((unsigned short*)out)[idx] = f2bf(val);
        else ((float*)out)[idx] = val;
      }
    }
  }
}

extern "C" void kernel_launch(void* const* d_in, const int* in_sizes, int n_in,
                              void* d_out, int out_size, void* d_ws, size_t ws_size,
                              hipStream_t stream) {
  (void)in_sizes; (void)n_in; (void)out_size; (void)ws_size;
  const void* x    = d_in[0];
  const void* mask = d_in[1];
  const void* wqv  = d_in[2];
  const void* rrb  = d_in[3];
  const void* rwb  = d_in[4];

  char* ws = (char*)d_ws;
  unsigned short* xh    = (unsigned short*)(ws);
  unsigned short* xl    = (unsigned short*)(ws + (8u << 20));
  unsigned short* Wh    = (unsigned short*)(ws + (16u << 20));
  unsigned short* Wl    = (unsigned short*)(ws + (20u << 20));
  float*          qwsf  = (float*)(ws + (24u << 20));
  unsigned short* vt    = (unsigned short*)(ws + (40u << 20));
  unsigned short* poshi = (unsigned short*)(ws + (48u << 20));
  unsigned short* poslo = (unsigned short*)(ws + (48u << 20) + (192u << 10));
  float*          posf  = (float*)(ws + (48u << 20) + (384u << 10));

  k_pos<<<dim3(272), 256, 0, stream>>>(poshi, poslo, posf);
  k_transpose<<<dim3(32, 16), 256, 0, stream>>>(wqv, mask, Wh, Wl);
  k_split_x<<<dim3(2048), 256, 0, stream>>>(x, mask, xh, xl);
  k_gemm<<<dim3(16, 32), 256, 0, stream>>>(xh, xl, Wh, Wl, qwsf, vt);
  k_attn<<<dim3(128, 4), 256, 0, stream>>>(xh, xl, qwsf, vt, poshi, poslo, posf, rrb, rwb, mask, (void*)d_out);
}

// Round 10
// 198.025 us; speedup vs baseline: 1.0438x; 1.0438x over previous
//
#include <hip/hip_runtime.h>
#include <stdint.h>

// Workspace layout (~48.6 MB):
//   xh    @ 0      : [4096][1024] bf16 (8 MB)  x hi part (= K hi)
//   xl    @ 8 MB   : [4096][1024] bf16 (8 MB)  x lo part
//   Wh    @ 16 MB  : [2048][1024] bf16 (4 MB)  W_qv^T hi
//   Wl    @ 20 MB  : [2048][1024] bf16 (4 MB)  W_qv^T lo
//   qwsf  @ 24 MB  : [8][16][512][64] f32 (16 MB) q full f32
//   vt    @ 40 MB  : [8][16][64][512] bf16 (8 MB) v transposed per head
//   poshi @ 48 MB          : [1088][64] bf16
//   poslo @ 48 MB + 192 KB : [1088][64] bf16
//   posf  @ 48 MB + 384 KB : [512][64] f32 = sin/cos(k*f_j)
//
// R10: (1) k_gemm v-half epilogue was writing bf16 at 1KB stride -> 32x
// write-allocate (WRITE_SIZE 128MB vs 24MB real). Now: LDS transpose
// (reuse K-loop LDS, [128][130] pad) + 256B-contiguous vt row writes.
// (2) pos/transpose/split_x fused into one k_prep_all launch.
// k_attn unchanged from round 9 (66.5us, FETCH 21.7MB, conflict-free).

typedef __attribute__((ext_vector_type(8))) short s8v;
typedef __attribute__((ext_vector_type(4))) float f4v;
typedef __attribute__((ext_vector_type(4))) unsigned short u16x4;

#define MFMA_BF16 __builtin_amdgcn_mfma_f32_16x16x32_bf16

__device__ __forceinline__ float bf2f(unsigned short s) {
  unsigned int u = ((unsigned int)s) << 16;
  float f;
  __builtin_memcpy(&f, &u, 4);
  return f;
}
__device__ __forceinline__ unsigned short f2bf(float f) {
  unsigned int u;
  __builtin_memcpy(&u, &f, 4);
  unsigned int r = (u + 0x7fffu + ((u >> 16) & 1u)) >> 16;
  return (unsigned short)r;
}
__device__ __forceinline__ bool is_bf16_in(const void* mask) {
  return (((const unsigned int*)mask)[0] & 0xFFFFu) != 0u;
}

// ---- fused prep: blocks [0,2048) split_x, [2048,2560) W transpose, [2560,2832) pos ----
__global__ __launch_bounds__(256) void k_prep_all(const void* __restrict__ X,
                                                  const void* __restrict__ W,
                                                  const void* __restrict__ mask,
                                                  unsigned short* __restrict__ xh,
                                                  unsigned short* __restrict__ xl,
                                                  unsigned short* __restrict__ Wh,
                                                  unsigned short* __restrict__ Wl,
                                                  unsigned short* __restrict__ poshi,
                                                  unsigned short* __restrict__ poslo,
                                                  float* __restrict__ posf) {
  __shared__ unsigned short th[64][65];
  __shared__ unsigned short tl[64][65];
  const bool isb = is_bf16_in(mask);
  const int blk = blockIdx.x;
  const int t = threadIdx.x;

  if (blk < 2048) {  // ---- split x -> xh, xl ----
    const int i = (blk * 256 + t) * 8;
    s8v oh, ol;
    if (isb) {
      oh = *(const s8v*)((const unsigned short*)X + i);
#pragma unroll
      for (int j = 0; j < 8; ++j) ol[j] = 0;
    } else {
      const float* xf = (const float*)X + i;
#pragma unroll
      for (int j = 0; j < 8; ++j) {
        float v = xf[j];
        unsigned short hi = f2bf(v);
        oh[j] = (short)hi;
        ol[j] = (short)f2bf(v - bf2f(hi));
      }
    }
    *(s8v*)(xh + i) = oh;
    *(s8v*)(xl + i) = ol;
  } else if (blk < 2560) {  // ---- W transpose + split ----
    const int id = blk - 2048;
    const int n0 = (id & 31) * 64;
    const int k0 = (id >> 5) * 64;
#pragma unroll
    for (int i = 0; i < 16; ++i) {
      int idx = t + i * 256;
      int kl = idx >> 6, nl = idx & 63;
      int src = (k0 + kl) * 2048 + n0 + nl;
      unsigned short hi, lo;
      if (isb) {
        hi = ((const unsigned short*)W)[src];
        lo = 0;
      } else {
        float v = ((const float*)W)[src];
        hi = f2bf(v);
        lo = f2bf(v - bf2f(hi));
      }
      th[nl][kl] = hi;
      tl[nl][kl] = lo;
    }
    __syncthreads();
#pragma unroll
    for (int i = 0; i < 16; ++i) {
      int idx = t + i * 256;
      int nl = idx >> 6, kl = idx & 63;
      Wh[(n0 + nl) * 1024 + k0 + kl] = th[nl][kl];
      Wl[(n0 + nl) * 1024 + k0 + kl] = tl[nl][kl];
    }
  } else {  // ---- pos tables ----
    int idx = (blk - 2560) * 256 + t;
    if (idx < 1088 * 64) {
      int l = idx >> 6, i = idx & 63;
      unsigned short hi = 0, lo = 0;
      if (l < 1024) {
        int j = i & 31;
        float f = expf(-0.2971077539347156f * (float)j);  // -ln(10000)/31
        float ang = (float)(l - 512) * f;
        float v = (i < 32) ? sinf(ang) : cosf(ang);
        hi = f2bf(v);
        lo = f2bf(v - bf2f(hi));
        if (l >= 512) posf[(l - 512) * 64 + i] = v;
      }
      poshi[idx] = hi;
      poslo[idx] = lo;
    }
  }
}

// ---- qv GEMM: reg-staged T14, stride-40 pad; v epilogue via LDS transpose ----
__global__ __launch_bounds__(256, 2) void k_gemm(const unsigned short* __restrict__ xh,
                                                 const unsigned short* __restrict__ xl,
                                                 const unsigned short* __restrict__ Wh,
                                                 const unsigned short* __restrict__ Wl,
                                                 float* __restrict__ qwsf,
                                                 unsigned short* __restrict__ vt) {
  __shared__ unsigned short SMEM[20480];  // 4 x 128*40 K-loop tiles; reused as [128][130] epilogue
  unsigned short* Ah = SMEM;
  unsigned short* Bh = SMEM + 5120;
  unsigned short* Al2 = SMEM + 10240;
  unsigned short* Bl2 = SMEM + 15360;
  const int m0 = blockIdx.y * 128;
  const int n0 = blockIdx.x * 128;
  const bool isq = (n0 < 1024);
  const int t = threadIdx.x;
  const int w = t >> 6, lane = t & 63;
  const int wr = w >> 1, wc = w & 1;
  const int l16 = lane & 15, g = lane >> 4;

  const int ca = t, cb = t + 256;
  const int ra = ca >> 2, ka = (ca & 3) * 8, rb = cb >> 2, kb = (cb & 3) * 8;

  f4v acc[4][4];
#pragma unroll
  for (int i = 0; i < 4; ++i)
#pragma unroll
    for (int j = 0; j < 4; ++j) acc[i][j] = (f4v){0.f, 0.f, 0.f, 0.f};

  s8v sA0, sA1, sB0, sB1, sC0, sC1, sD0, sD1;
  auto issue = [&](int k0) {
    sA0 = *(const s8v*)&xh[(m0 + ra) * 1024 + k0 + ka];
    sA1 = *(const s8v*)&xh[(m0 + rb) * 1024 + k0 + kb];
    sB0 = *(const s8v*)&Wh[(n0 + ra) * 1024 + k0 + ka];
    sB1 = *(const s8v*)&Wh[(n0 + rb) * 1024 + k0 + kb];
    if (isq) {
      sC0 = *(const s8v*)&xl[(m0 + ra) * 1024 + k0 + ka];
      sC1 = *(const s8v*)&xl[(m0 + rb) * 1024 + k0 + kb];
      sD0 = *(const s8v*)&Wl[(n0 + ra) * 1024 + k0 + ka];
      sD1 = *(const s8v*)&Wl[(n0 + rb) * 1024 + k0 + kb];
    }
  };
  auto commit = [&]() {
    *(s8v*)&Ah[ra * 40 + ka] = sA0;
    *(s8v*)&Ah[rb * 40 + kb] = sA1;
    *(s8v*)&Bh[ra * 40 + ka] = sB0;
    *(s8v*)&Bh[rb * 40 + kb] = sB1;
    if (isq) {
      *(s8v*)&Al2[ra * 40 + ka] = sC0;
      *(s8v*)&Al2[rb * 40 + kb] = sC1;
      *(s8v*)&Bl2[ra * 40 + ka] = sD0;
      *(s8v*)&Bl2[rb * 40 + kb] = sD1;
    }
  };
  issue(0);
  commit();
  __syncthreads();

#pragma unroll 1
  for (int t32 = 0; t32 < 32; ++t32) {
    if (t32 < 31) issue((t32 + 1) * 32);  // T14: in flight during compute
    s8v afh[4], bfh[4];
#pragma unroll
    for (int i = 0; i < 4; ++i) afh[i] = *(const s8v*)&Ah[(wr * 64 + i * 16 + l16) * 40 + g * 8];
#pragma unroll
    for (int j = 0; j < 4; ++j) bfh[j] = *(const s8v*)&Bh[(wc * 64 + j * 16 + l16) * 40 + g * 8];
    if (isq) {
      s8v afl[4], bfl[4];
#pragma unroll
      for (int i = 0; i < 4; ++i) afl[i] = *(const s8v*)&Al2[(wr * 64 + i * 16 + l16) * 40 + g * 8];
#pragma unroll
      for (int j = 0; j < 4; ++j) bfl[j] = *(const s8v*)&Bl2[(wc * 64 + j * 16 + l16) * 40 + g * 8];
#pragma unroll
      for (int i = 0; i < 4; ++i)
#pragma unroll
        for (int j = 0; j < 4; ++j) {
          acc[i][j] = MFMA_BF16(afh[i], bfh[j], acc[i][j], 0, 0, 0);
          acc[i][j] = MFMA_BF16(afl[i], bfh[j], acc[i][j], 0, 0, 0);
          acc[i][j] = MFMA_BF16(afh[i], bfl[j], acc[i][j], 0, 0, 0);
        }
    } else {
#pragma unroll
      for (int i = 0; i < 4; ++i)
#pragma unroll
        for (int j = 0; j < 4; ++j) acc[i][j] = MFMA_BF16(afh[i], bfh[j], acc[i][j], 0, 0, 0);
    }
    if (t32 < 31) {
      __syncthreads();
      commit();
      __syncthreads();
    }
  }

  if (isq) {
    // q epilogue: f32, d-contiguous (coalesced) — unchanged
#pragma unroll
    for (int i = 0; i < 4; ++i) {
#pragma unroll
      for (int j = 0; j < 4; ++j) {
        int col = n0 + wc * 64 + j * 16 + l16;
#pragma unroll
        for (int jj = 0; jj < 4; ++jj) {
          int row = m0 + wr * 64 + i * 16 + g * 4 + jj;
          int bb = row >> 9, l = row & 511;
          int hh = col >> 6, d = col & 63;
          qwsf[((bb * 16 + hh) * 512 + l) * 64 + d] = acc[i][j][jj];
        }
      }
    }
  } else {
    // v epilogue: transpose through LDS, then 256B-contiguous vt writes
    __syncthreads();  // K-loop LDS reads done before overwrite
#pragma unroll
    for (int i = 0; i < 4; ++i) {
#pragma unroll
      for (int j = 0; j < 4; ++j) {
        const int nl = wc * 64 + j * 16 + l16;
        const int mlb = wr * 64 + i * 16 + g * 4;
        u16x4 pv;
#pragma unroll
        for (int jj = 0; jj < 4; ++jj) pv[jj] = f2bf(acc[i][j][jj]);
        *(u16x4*)&SMEM[nl * 130 + mlb] = pv;
      }
    }
    __syncthreads();
    const int bb = m0 >> 9;
    const int ml0 = m0 & 511;
    const int cchunk = t & 15;  // 16 x 8-elem chunks per 128-wide row
    const int r0 = t >> 4;      // 16 rows per pass
#pragma unroll
    for (int p = 0; p < 8; ++p) {
      int nl = r0 + p * 16;
      int c2 = (n0 - 1024) + nl;
      int hh = c2 >> 6, d = c2 & 63;
      s8v val = *(const s8v*)&SMEM[nl * 130 + cchunk * 8];
      *(s8v*)&vt[((bb * 16 + hh) * 64 + d) * 512 + ml0 + cchunk * 8] = val;
    }
  }
}

// -------- fused relative attention: 2 q-tiles/block, XCD-local KV (unchanged) --------
__global__ __launch_bounds__(256, 2) void k_attn(const unsigned short* __restrict__ xh,
                                                 const unsigned short* __restrict__ xl,
                                                 const float* __restrict__ qwsf,
                                                 const unsigned short* __restrict__ vt,
                                                 const unsigned short* __restrict__ poshi,
                                                 const unsigned short* __restrict__ poslo,
                                                 const float* __restrict__ posf,
                                                 const void* __restrict__ rrb,
                                                 const void* __restrict__ rwb,
                                                 const void* __restrict__ mask,
                                                 void* __restrict__ out) {
  __shared__ unsigned short Kh[64 * 64];
  __shared__ unsigned short Kl[64 * 64];
  __shared__ unsigned short Vv[64 * 64];
  __shared__ unsigned short Th[64 * 64];
  __shared__ unsigned short Tl[64 * 64];
  __shared__ unsigned short P[4][16][68];

  const bool isb = is_bf16_in(mask);
  const int bh = blockIdx.x;
  const int qp = blockIdx.y;
  const int b = bh >> 4, h = bh & 15;
  const int q0 = qp << 7;
  const int t = threadIdx.x;
  const int w = t >> 6;
  const int lane = t & 63;
  const int l16 = lane & 15;
  const int g = lane >> 4;
  const int bh64 = (b * 16 + h) * 64;

  const int srow = t >> 3;
  const int swz = ((t & 7) ^ (srow & 7)) << 3;
  const int scc = (t & 7) * 8;

#pragma unroll
  for (int i = 0; i < 2; ++i) {
    int row = srow + i * 32;
    *(s8v*)&Kh[row * 64 + swz] = *(const s8v*)&xh[(b * 512 + row) * 1024 + h * 64 + scc];
    *(s8v*)&Kl[row * 64 + swz] = *(const s8v*)&xl[(b * 512 + row) * 1024 + h * 64 + scc];
    *(s8v*)&Vv[row * 64 + swz] = *(const s8v*)&vt[(bh64 + row) * 512 + scc];
    *(s8v*)&Th[row * 64 + swz] = *(const s8v*)&poshi[(512 + row) * 64 + scc];
    *(s8v*)&Tl[row * 64 + swz] = *(const s8v*)&poslo[(512 + row) * 64 + scc];
  }

  s8v qrh[2][2], qrl[2][2], qth[2][2], qtl[2][2];
#pragma unroll
  for (int hh = 0; hh < 2; ++hh) {
    const int qrow = q0 + hh * 64 + (w << 4) + l16;
    const float* qb = &qwsf[((b * 16 + h) * 512 + qrow) * 64];
    float qw2[2][8];
#pragma unroll
    for (int f = 0; f < 2; ++f) {
      int d0 = f * 32 + g * 8;
#pragma unroll
      for (int j = 0; j < 8; ++j) {
        float qf = qb[d0 + j];
        float b1 = isb ? bf2f(((const unsigned short*)rrb)[h * 64 + d0 + j])
                       : ((const float*)rrb)[h * 64 + d0 + j];
        float b2 = isb ? bf2f(((const unsigned short*)rwb)[h * 64 + d0 + j])
                       : ((const float*)rwb)[h * 64 + d0 + j];
        float s1 = qf + b1;
        unsigned short h1 = f2bf(s1);
        qrh[hh][f][j] = (short)h1;
        qrl[hh][f][j] = (short)f2bf(s1 - bf2f(h1));
        qw2[f][j] = qf + b2;
      }
    }
#pragma unroll
    for (int j = 0; j < 8; ++j) {
      int jd = g * 8 + j;
      float s = posf[qrow * 64 + jd];
      float c = posf[qrow * 64 + 32 + jd];
      float qs = qw2[0][j], qc = qw2[1][j];
      float Qp = qs * c + qc * s;
      float Qpp = qc * c - qs * s;
      unsigned short h0 = f2bf(Qp);
      qth[hh][0][j] = (short)h0;
      qtl[hh][0][j] = (short)f2bf(Qp - bf2f(h0));
      unsigned short h1 = f2bf(Qpp);
      qth[hh][1][j] = (short)h1;
      qtl[hh][1][j] = (short)f2bf(Qpp - bf2f(h1));
    }
  }

  f4v accO[2][4];
#pragma unroll
  for (int hh = 0; hh < 2; ++hh)
#pragma unroll
    for (int d = 0; d < 4; ++d) accO[hh][d] = (f4v){0.f, 0.f, 0.f, 0.f};
  float mrun[2][4], lrun[2][4];
#pragma unroll
  for (int hh = 0; hh < 2; ++hh)
#pragma unroll
    for (int jj = 0; jj < 4; ++jj) { mrun[hh][jj] = -3.0e38f; lrun[hh][jj] = 0.f; }

  __syncthreads();

#pragma unroll 1
  for (int kt = 0; kt < 8; ++kt) {
    const int k0 = kt << 6;

    s8v nKh[2], nKl[2], nV[2], nTh[2], nTl[2];
    const bool hasNext = (kt < 7);
    if (hasNext) {
      const int k0n = k0 + 64;
#pragma unroll
      for (int i = 0; i < 2; ++i) {
        int row = srow + i * 32;
        nKh[i] = *(const s8v*)&xh[(b * 512 + k0n + row) * 1024 + h * 64 + scc];
        nKl[i] = *(const s8v*)&xl[(b * 512 + k0n + row) * 1024 + h * 64 + scc];
        nV[i] = *(const s8v*)&vt[(bh64 + row) * 512 + k0n + scc];
        nTh[i] = *(const s8v*)&poshi[(512 + k0n + row) * 64 + scc];
        nTl[i] = *(const s8v*)&poslo[(512 + k0n + row) * 64 + scc];
      }
    }

    float mv[4];
#pragma unroll
    for (int ct = 0; ct < 4; ++ct) {
      int mi = b * 512 + k0 + ct * 16 + l16;
      mv[ct] = isb ? bf2f(((const unsigned short*)mask)[mi]) : ((const float*)mask)[mi];
    }

#pragma unroll
    for (int hh = 0; hh < 2; ++hh) {
      f4v acc[4];
#pragma unroll
      for (int ct = 0; ct < 4; ++ct) acc[ct] = (f4v){0.f, 0.f, 0.f, 0.f};
#pragma unroll
      for (int f = 0; f < 2; ++f) {
#pragma unroll
        for (int ct = 0; ct < 4; ++ct) {
          const int kr = ct * 16 + l16;
          const int eo = (((4 * f + g) ^ (l16 & 7)) << 3);
          s8v kh = *(const s8v*)&Kh[kr * 64 + eo];
          s8v klo = *(const s8v*)&Kl[kr * 64 + eo];
          s8v ph = *(const s8v*)&Th[kr * 64 + eo];
          s8v pl = *(const s8v*)&Tl[kr * 64 + eo];
          acc[ct] = MFMA_BF16(qrh[hh][f], kh, acc[ct], 0, 0, 0);
          acc[ct] = MFMA_BF16(qrl[hh][f], kh, acc[ct], 0, 0, 0);
          acc[ct] = MFMA_BF16(qrh[hh][f], klo, acc[ct], 0, 0, 0);
          acc[ct] = MFMA_BF16(qth[hh][f], ph, acc[ct], 0, 0, 0);
          acc[ct] = MFMA_BF16(qtl[hh][f], ph, acc[ct], 0, 0, 0);
          acc[ct] = MFMA_BF16(qth[hh][f], pl, acc[ct], 0, 0, 0);
        }
      }

      float sv[4][4];
#pragma unroll
      for (int ct = 0; ct < 4; ++ct) {
#pragma unroll
        for (int jj = 0; jj < 4; ++jj) {
          float s = acc[ct][jj] * mv[ct];
          if (s == 0.f) s = -__builtin_inff();
          sv[ct][jj] = s;
        }
      }

      float sc[4];
#pragma unroll
      for (int jj = 0; jj < 4; ++jj) {
        float pm = fmaxf(fmaxf(sv[0][jj], sv[1][jj]), fmaxf(sv[2][jj], sv[3][jj]));
        pm = fmaxf(pm, __shfl_xor(pm, 1));
        pm = fmaxf(pm, __shfl_xor(pm, 2));
        pm = fmaxf(pm, __shfl_xor(pm, 4));
        pm = fmaxf(pm, __shfl_xor(pm, 8));
        float mnew = fmaxf(mrun[hh][jj], pm);
        float scale = __expf(mrun[hh][jj] - mnew);
        float ps = 0.f;
#pragma unroll
        for (int ct = 0; ct < 4; ++ct) {
          float p = __expf(sv[ct][jj] - mnew);
          unsigned short pb = f2bf(p);
          P[w][4 * g + jj][ct * 16 + l16] = pb;
          ps += bf2f(pb);
        }
        ps += __shfl_xor(ps, 1);
        ps += __shfl_xor(ps, 2);
        ps += __shfl_xor(ps, 4);
        ps += __shfl_xor(ps, 8);
        lrun[hh][jj] = lrun[hh][jj] * scale + ps;
        mrun[hh][jj] = mnew;
        sc[jj] = scale;
      }

#pragma unroll
      for (int d = 0; d < 4; ++d)
#pragma unroll
        for (int jj = 0; jj < 4; ++jj) accO[hh][d][jj] *= sc[jj];
#pragma unroll
      for (int ks = 0; ks < 2; ++ks) {
        s8v pf = *(const s8v*)&P[w][l16][ks * 32 + g * 8];
#pragma unroll
        for (int d = 0; d < 4; ++d) {
          const int vr = d * 16 + l16;
          const int eo = (((4 * ks + g) ^ (l16 & 7)) << 3);
          s8v vf = *(const s8v*)&Vv[vr * 64 + eo];
          accO[hh][d] = MFMA_BF16(pf, vf, accO[hh][d], 0, 0, 0);
        }
      }
    }

    __syncthreads();
    if (hasNext) {
#pragma unroll
      for (int i = 0; i < 2; ++i) {
        int row = srow + i * 32;
        *(s8v*)&Kh[row * 64 + swz] = nKh[i];
        *(s8v*)&Kl[row * 64 + swz] = nKl[i];
        *(s8v*)&Vv[row * 64 + swz] = nV[i];
        *(s8v*)&Th[row * 64 + swz] = nTh[i];
        *(s8v*)&Tl[row * 64 + swz] = nTl[i];
      }
    }
    __syncthreads();
  }

#pragma unroll
  for (int hh = 0; hh < 2; ++hh) {
    float inv[4];
#pragma unroll
    for (int jj = 0; jj < 4; ++jj) inv[jj] = 1.0f / lrun[hh][jj];
#pragma unroll
    for (int d = 0; d < 4; ++d) {
#pragma unroll
      for (int jj = 0; jj < 4; ++jj) {
        int row = q0 + hh * 64 + (w << 4) + 4 * g + jj;
        int idx = (b * 512 + row) * 1024 + h * 64 + d * 16 + l16;
        float val = accO[hh][d][jj] * inv[jj];
        if (isb) ((unsigned short*)out)[idx] = f2bf(val);
        else ((float*)out)[idx] = val;
      }
    }
  }
}

extern "C" void kernel_launch(void* const* d_in, const int* in_sizes, int n_in,
                              void* d_out, int out_size, void* d_ws, size_t ws_size,
                              hipStream_t stream) {
  (void)in_sizes; (void)n_in; (void)out_size; (void)ws_size;
  const void* x    = d_in[0];
  const void* mask = d_in[1];
  const void* wqv  = d_in[2];
  const void* rrb  = d_in[3];
  const void* rwb  = d_in[4];

  char* ws = (char*)d_ws;
  unsigned short* xh    = (unsigned short*)(ws);
  unsigned short* xl    = (unsigned short*)(ws + (8u << 20));
  unsigned short* Wh    = (unsigned short*)(ws + (16u << 20));
  unsigned short* Wl    = (unsigned short*)(ws + (20u << 20));
  float*          qwsf  = (float*)(ws + (24u << 20));
  unsigned short* vt    = (unsigned short*)(ws + (40u << 20));
  unsigned short* poshi = (unsigned short*)(ws + (48u << 20));
  unsigned short* poslo = (unsigned short*)(ws + (48u << 20) + (192u << 10));
  float*          posf  = (float*)(ws + (48u << 20) + (384u << 10));

  k_prep_all<<<dim3(2832), 256, 0, stream>>>(x, wqv, mask, xh, xl, Wh, Wl, poshi, poslo, posf);
  k_gemm<<<dim3(16, 32), 256, 0, stream>>>(xh, xl, Wh, Wl, qwsf, vt);
  k_attn<<<dim3(128, 4), 256, 0, stream>>>(xh, xl, qwsf, vt, poshi, poslo, posf, rrb, rwb, mask, (void*)d_out);
}